// Round 5
// baseline (24.110 us; speedup 1.0000x reference)
//
#include <hip/hip_runtime.h>

// DMLoss: B=1024, Np=Ng=128, T=10.
// Round 5: round-4 was LDS-pipe bound (~11us of broadcast ds_reads + 2.8us of
// double-shfl bpermutes vs only ~3us VALU). Inner-loop tables are wave-uniform
// (index = quarter + loop counter) -> readfirstlane + uniform global reads so
// the compiler selects s_load (SMEM pipe); segment math recomputed in-loop on
// the idle VALU. LDS kept only for one-time staging + argmin combine. Float
// partials; shuffle-reduce only in waves 0-1. First barrier moved after scans.

constexpr int NP = 128;
constexpr int NG = 128;

__global__ __launch_bounds__(512) void dm_main(
    const float* __restrict__ ini,   // [B, NP, 2]
    const float* __restrict__ pp,    // [B, NP, 2]
    const float* __restrict__ gt,    // [B, NG, 2]
    const float* __restrict__ mask,  // [B, NG]
    float* __restrict__ partial)     // [B, 3] {pred2gt_sum, masked_sum, mask_sum}
{
    const int b   = blockIdx.x;
    const int tid = threadIdx.x;

    __shared__ float2 s_gt [NG];
    __shared__ float2 s_pp [NP];
    __shared__ float  s_bd1[512], s_bi1[512], s_bd2[512], s_bi2[512];
    __shared__ float  s_red[6];

    const float* gtb  = gt  + (size_t)b * 256;
    const float* inib = ini + (size_t)b * 256;
    const float* ppb  = pp  + (size_t)b * 256;

    // One-time staging for combine-phase gathers (no barrier needed until after
    // the scan loops, which do not read LDS).
    if (tid < 256) {
        ((float*)s_gt)[tid] = gtb[tid];
        ((float*)s_pp)[tid] = ppb[tid];
    }

    const int p  = tid & (NP - 1);
    // Wave-uniform quarter start, forced into an SGPR so in-loop global reads
    // have provably uniform addresses -> s_load (SMEM pipe, zero LDS/VMEM).
    const int s0 = __builtin_amdgcn_readfirstlane((tid >> 7) << 5);  // 0,32,64,96

    const float2 q    = ((const float2*)inib)[p];   // coalesced per-lane
    const float2 gv   = ((const float2*)gtb)[p];    // coalesced per-lane
    const float  mval = (tid < NP) ? mask[(size_t)b * NG + tid] : 0.0f;  // prefetch

    // ---- Part 1 scan: nearest interpolated gt point (32 segments/thread) ----
    {
        float best  = 3.4e38f;
        float bif   = 0.0f;
        float basef = (float)(s0 * 10);
        float2 pv = ((const float2*)gtb)[(s0 + NG - 1) & (NG - 1)];  // uniform
        #pragma unroll 8
        for (int k = 0; k < 32; ++k) {
            const float2 cv = ((const float2*)gtb)[s0 + k];          // uniform s_load
            const float ex = cv.x - pv.x, ey = cv.y - pv.y;
            const float wx = q.x - pv.x,  wy = q.y - pv.y;
            const float ee = fmaxf(fmaf(ey, ey, ex * ex), 1e-30f);
            const float s10 = 10.0f * __builtin_amdgcn_rcpf(ee);
            const float dot = fmaf(wy, ey, wx * ex);
            float tc = rintf(dot * s10);
            tc = fminf(fmaxf(tc, 0.0f), 9.0f);
            const float u   = tc * 0.1f;             // model distance only
            const float dqx = fmaf(-u, ex, wx);
            const float dqy = fmaf(-u, ey, wy);
            const float d   = fmaf(dqy, dqy, dqx * dqx);
            const float cand = basef + tc;
            bif  = (d < best) ? cand : bif;          // strict <: first occurrence
            best = fminf(d, best);
            basef += 10.0f;
            pv = cv;
        }
        s_bd1[tid] = best;
        s_bi1[tid] = bif;
    }

    // ---- Part 2 scan: nearest pred point per gt vertex (32 preds/thread) ----
    {
        float bd  = 3.4e38f;
        float bjf = 0.0f;
        float jf  = (float)s0;
        #pragma unroll 8
        for (int k = 0; k < 32; ++k) {
            const float2 pvt = ((const float2*)inib)[s0 + k];        // uniform s_load
            const float dx = gv.x - pvt.x, dy = gv.y - pvt.y;
            const float d  = fmaf(dy, dy, dx * dx);
            bjf = (d < bd) ? jf : bjf;
            bd  = fminf(d, bd);
            jf += 1.0f;
        }
        s_bd2[tid] = bd;
        s_bi2[tid] = bjf;
    }
    __syncthreads();   // covers staging writes + s_bd/s_bi writes

    float l_a = 0.0f, l_c = 0.0f, l_m = 0.0f;
    if (tid < NP) {
        // Part 1 combine: ascending quarter order, strict < keeps first
        // occurrence (jnp.argmin semantics).
        float bd = s_bd1[tid];
        float bi = s_bi1[tid];
        #pragma unroll
        for (int qq = 1; qq < 4; ++qq) {
            const float d2 = s_bd1[tid + qq * 128];
            const float i2 = s_bi1[tid + qq * 128];
            bi = (d2 < bd) ? i2 : bi;
            bd = fminf(d2, bd);
        }
        const int idx = (int)bi;
        const int n = idx / 10;          // compile-time magic-mul
        const int t = idx - n * 10;
        const float step = (float)t / 10.0f;   // exact ref: arange(T)/T
        const float om   = 1.0f - step;
        const float2 c  = s_gt[n];
        const float2 pr = s_gt[(n + NG - 1) & (NG - 1)];
        const float nx = c.x * step + pr.x * om;
        const float ny = c.y * step + pr.y * om;
        const float2 mp = s_pp[tid];
        l_a = fabsf(mp.x - nx) + fabsf(mp.y - ny);

        // Part 2 combine
        float cd = s_bd2[tid];
        float cj = s_bi2[tid];
        #pragma unroll
        for (int qq = 1; qq < 4; ++qq) {
            const float d2 = s_bd2[tid + qq * 128];
            const float j2 = s_bi2[tid + qq * 128];
            cj = (d2 < cd) ? j2 : cj;
            cd = fminf(d2, cd);
        }
        const float2 npt = s_pp[(int)cj];
        const float2 gvv = s_gt[tid];
        l_c = mval * (fabsf(npt.x - gvv.x) + fabsf(npt.y - gvv.y));
        l_m = 2.0f * mval;
    }

    // Only waves 0-1 carry data: float shuffle-reduce there, skip elsewhere.
    const int wid = tid >> 6, lane = tid & 63;
    if (wid < 2) {
        for (int off = 32; off > 0; off >>= 1) {
            l_a += __shfl_down(l_a, off);
            l_c += __shfl_down(l_c, off);
            l_m += __shfl_down(l_m, off);
        }
        if (lane == 0) {
            s_red[wid * 3 + 0] = l_a;
            s_red[wid * 3 + 1] = l_c;
            s_red[wid * 3 + 2] = l_m;
        }
    }
    __syncthreads();
    if (tid == 0) {
        partial[(size_t)b * 3 + 0] = s_red[0] + s_red[3];
        partial[(size_t)b * 3 + 1] = s_red[1] + s_red[4];
        partial[(size_t)b * 3 + 2] = s_red[2] + s_red[5];
    }
}

__global__ __launch_bounds__(256) void dm_final(
    const float* __restrict__ partial, int nb, double inv_count, float* __restrict__ out)
{
    const int tid = threadIdx.x;
    double a = 0.0, c = 0.0, d = 0.0;
    for (int b = tid; b < nb; b += 256) {
        a += (double)partial[(size_t)b * 3 + 0];
        c += (double)partial[(size_t)b * 3 + 1];
        d += (double)partial[(size_t)b * 3 + 2];
    }
    for (int off = 32; off > 0; off >>= 1) {
        a += __shfl_down(a, off);
        c += __shfl_down(c, off);
        d += __shfl_down(d, off);
    }
    __shared__ double s[12];
    const int wid = tid >> 6, lane = tid & 63;
    if (lane == 0) { s[wid * 3] = a; s[wid * 3 + 1] = c; s[wid * 3 + 2] = d; }
    __syncthreads();
    if (tid == 0) {
        const double at = s[0] + s[3] + s[6] + s[9];
        const double ct = s[1] + s[4] + s[7] + s[10];
        const double dt = s[2] + s[5] + s[8] + s[11];
        const double loss = ct / (dt + 1.0) + at * inv_count;
        out[0] = (float)(loss * 0.5);
    }
}

extern "C" void kernel_launch(void* const* d_in, const int* in_sizes, int n_in,
                              void* d_out, int out_size, void* d_ws, size_t ws_size,
                              hipStream_t stream) {
    const float* ini  = (const float*)d_in[0];
    const float* pp   = (const float*)d_in[1];
    const float* gt   = (const float*)d_in[2];
    const float* mask = (const float*)d_in[3];
    float* out = (float*)d_out;

    const int B = in_sizes[0] / (NP * 2);
    float* partial = (float*)d_ws;

    dm_main<<<B, 512, 0, stream>>>(ini, pp, gt, mask, partial);
    const double inv_count = 1.0 / ((double)B * NP * 2);
    dm_final<<<1, 256, 0, stream>>>(partial, B, inv_count, out);
}

// Round 6
// 20.559 us; speedup vs baseline: 1.1727x; 1.1727x over previous
//
#include <hip/hip_runtime.h>

// DMLoss: B=1024, Np=Ng=128, T=10.
// Round 6: round-4 structure (LDS tables — round-5's SMEM gamble regressed),
// with LDS cost per distance-eval cut ~3x:
//  - 2 points per thread (pair pr, pr+64) x 16 segments/group: each broadcast
//    table read amortized over 2 evals. 64 pairs x 8 groups = 512 threads.
//  - part1 table entry packed into ONE b128 {pv.x,pv.y,ex,ey}; 10/|e|^2
//    recomputed in-loop via v_rcp on the idle VALU (kills the extra b32 read).
//  - per-thread results stored as one float4 {d0,i0,d1,i1} (single b128).
// Float partials; 2-wave float shuffle reduce; two-kernel finish (device
// fences proved poisonous in round 3).

constexpr int NP = 128;
constexpr int NG = 128;

__global__ __launch_bounds__(512) void dm_main(
    const float* __restrict__ ini,   // [B, NP, 2]
    const float* __restrict__ pp,    // [B, NP, 2]
    const float* __restrict__ gt,    // [B, NG, 2]
    const float* __restrict__ mask,  // [B, NG]
    float* __restrict__ partial)     // [B, 3] {pred2gt_sum, masked_sum, mask_sum}
{
    const int b   = blockIdx.x;
    const int tid = threadIdx.x;

    __shared__ float2 s_gt [NG];
    __shared__ float2 s_ini[NP];
    __shared__ float2 s_pp [NP];
    __shared__ float4 s_seg[NG];       // {pv.x, pv.y, ex, ey}
    __shared__ float4 s_r1 [8][64];    // {d0, i0, d1, i1} per (group, pair)
    __shared__ float4 s_r2 [8][64];
    __shared__ float  s_red[6];

    const float2* gtb  = (const float2*)(gt  + (size_t)b * 256);
    const float2* inib = (const float2*)(ini + (size_t)b * 256);
    const float2* ppb  = (const float2*)(pp  + (size_t)b * 256);

    // Staging (split across waves; all global, no LDS deps before barrier)
    if (tid < 128) {
        const float2 cv = gtb[tid];
        const float2 pv = gtb[(tid + 127) & 127];
        s_gt [tid] = cv;
        s_seg[tid] = make_float4(pv.x, pv.y, cv.x - pv.x, cv.y - pv.y);
    } else if (tid < 256) {
        s_ini[tid - 128] = inib[tid - 128];
    } else if (tid < 384) {
        s_pp [tid - 256] = ppb[tid - 256];
    }

    const int pr = tid & 63;           // point-pair index
    const int g  = tid >> 6;           // segment/pred group, 0..7 (wave-uniform)
    const float2 q0 = inib[pr];        // part-1 query points (L1-hot re-reads)
    const float2 q1 = inib[pr + 64];
    const float2 g0 = gtb [pr];        // part-2 query points
    const float2 g1 = gtb [pr + 64];
    const float  mval = (tid < NP) ? mask[(size_t)b * NG + tid] : 0.0f;
    __syncthreads();

    // ---- Part 1 scan: 16 segments x 2 points per thread ----
    {
        float bd0 = 3.4e38f, bi0 = 0.0f, bd1 = 3.4e38f, bi1 = 0.0f;
        float basef = (float)(g * 160);         // segment index * 10
        const int s0 = g * 16;
        #pragma unroll
        for (int k = 0; k < 16; ++k) {
            const float4 sg = s_seg[s0 + k];    // broadcast ds_read_b128
            const float ex = sg.z, ey = sg.w;
            const float ee  = fmaxf(fmaf(ex, ex, ey * ey), 1e-30f);
            const float s10 = 10.0f * __builtin_amdgcn_rcpf(ee);
            // point 0
            {
                const float wx = q0.x - sg.x, wy = q0.y - sg.y;
                const float dot = fmaf(wy, ey, wx * ex);
                float tc = rintf(dot * s10);
                tc = __builtin_amdgcn_fmed3f(tc, 0.0f, 9.0f);
                const float u   = tc * 0.1f;    // model distance only
                const float dqx = fmaf(-u, ex, wx);
                const float dqy = fmaf(-u, ey, wy);
                const float d   = fmaf(dqy, dqy, dqx * dqx);
                const float cand = basef + tc;
                bi0 = (d < bd0) ? cand : bi0;   // strict <: first occurrence
                bd0 = fminf(d, bd0);
            }
            // point 1
            {
                const float wx = q1.x - sg.x, wy = q1.y - sg.y;
                const float dot = fmaf(wy, ey, wx * ex);
                float tc = rintf(dot * s10);
                tc = __builtin_amdgcn_fmed3f(tc, 0.0f, 9.0f);
                const float u   = tc * 0.1f;
                const float dqx = fmaf(-u, ex, wx);
                const float dqy = fmaf(-u, ey, wy);
                const float d   = fmaf(dqy, dqy, dqx * dqx);
                const float cand = basef + tc;
                bi1 = (d < bd1) ? cand : bi1;
                bd1 = fminf(d, bd1);
            }
            basef += 10.0f;
        }
        s_r1[g][pr] = make_float4(bd0, bi0, bd1, bi1);   // single ds_write_b128
    }

    // ---- Part 2 scan: 16 preds x 2 gt vertices per thread ----
    {
        float bd0 = 3.4e38f, bj0 = 0.0f, bd1 = 3.4e38f, bj1 = 0.0f;
        float jf = (float)(g * 16);
        const int j0 = g * 16;
        #pragma unroll
        for (int k = 0; k < 16; ++k) {
            const float2 pv = s_ini[j0 + k];    // broadcast ds_read_b64
            {
                const float dx = g0.x - pv.x, dy = g0.y - pv.y;
                const float d  = fmaf(dy, dy, dx * dx);
                bj0 = (d < bd0) ? jf : bj0;
                bd0 = fminf(d, bd0);
            }
            {
                const float dx = g1.x - pv.x, dy = g1.y - pv.y;
                const float d  = fmaf(dy, dy, dx * dx);
                bj1 = (d < bd1) ? jf : bj1;
                bd1 = fminf(d, bd1);
            }
            jf += 1.0f;
        }
        s_r2[g][pr] = make_float4(bd0, bj0, bd1, bj1);
    }
    __syncthreads();

    float l_a = 0.0f, l_c = 0.0f, l_m = 0.0f;
    if (tid < NP) {
        const int slot = tid >> 6;     // wave-uniform: wave0 -> .x/.y, wave1 -> .z/.w
        const int ln   = tid & 63;

        // Part 1 combine: ascending group order, strict < = first occurrence
        float bd = 3.4e38f, bi = 0.0f;
        #pragma unroll
        for (int gg = 0; gg < 8; ++gg) {
            const float4 r  = s_r1[gg][ln];     // coalesced ds_read_b128
            const float d2 = slot ? r.z : r.x;
            const float i2 = slot ? r.w : r.y;
            bi = (d2 < bd) ? i2 : bi;
            bd = fminf(d2, bd);
        }
        const int idx = (int)bi;
        const int n = idx / 10;                 // magic-mul
        const int t = idx - n * 10;
        const float step = (float)t / 10.0f;    // exact ref: arange(T)/T
        const float om   = 1.0f - step;
        const float2 c  = s_gt[n];
        const float2 prv = s_gt[(n + NG - 1) & (NG - 1)];
        const float nx = c.x * step + prv.x * om;
        const float ny = c.y * step + prv.y * om;
        const float2 mp = s_pp[tid];
        l_a = fabsf(mp.x - nx) + fabsf(mp.y - ny);

        // Part 2 combine
        float cd = 3.4e38f, cj = 0.0f;
        #pragma unroll
        for (int gg = 0; gg < 8; ++gg) {
            const float4 r  = s_r2[gg][ln];
            const float d2 = slot ? r.z : r.x;
            const float j2 = slot ? r.w : r.y;
            cj = (d2 < cd) ? j2 : cj;
            cd = fminf(d2, cd);
        }
        const float2 npt = s_pp[(int)cj];
        const float2 gvv = s_gt[tid];
        l_c = mval * (fabsf(npt.x - gvv.x) + fabsf(npt.y - gvv.y));
        l_m = 2.0f * mval;
    }

    // Float shuffle-reduce, waves 0-1 only
    const int wid = tid >> 6, lane = tid & 63;
    if (wid < 2) {
        for (int off = 32; off > 0; off >>= 1) {
            l_a += __shfl_down(l_a, off);
            l_c += __shfl_down(l_c, off);
            l_m += __shfl_down(l_m, off);
        }
        if (lane == 0) {
            s_red[wid * 3 + 0] = l_a;
            s_red[wid * 3 + 1] = l_c;
            s_red[wid * 3 + 2] = l_m;
        }
    }
    __syncthreads();
    if (tid == 0) {
        partial[(size_t)b * 3 + 0] = s_red[0] + s_red[3];
        partial[(size_t)b * 3 + 1] = s_red[1] + s_red[4];
        partial[(size_t)b * 3 + 2] = s_red[2] + s_red[5];
    }
}

__global__ __launch_bounds__(256) void dm_final(
    const float* __restrict__ partial, int nb, double inv_count, float* __restrict__ out)
{
    const int tid = threadIdx.x;
    double a = 0.0, c = 0.0, d = 0.0;
    for (int b = tid; b < nb; b += 256) {
        a += (double)partial[(size_t)b * 3 + 0];
        c += (double)partial[(size_t)b * 3 + 1];
        d += (double)partial[(size_t)b * 3 + 2];
    }
    for (int off = 32; off > 0; off >>= 1) {
        a += __shfl_down(a, off);
        c += __shfl_down(c, off);
        d += __shfl_down(d, off);
    }
    __shared__ double s[12];
    const int wid = tid >> 6, lane = tid & 63;
    if (lane == 0) { s[wid * 3] = a; s[wid * 3 + 1] = c; s[wid * 3 + 2] = d; }
    __syncthreads();
    if (tid == 0) {
        const double at = s[0] + s[3] + s[6] + s[9];
        const double ct = s[1] + s[4] + s[7] + s[10];
        const double dt = s[2] + s[5] + s[8] + s[11];
        const double loss = ct / (dt + 1.0) + at * inv_count;
        out[0] = (float)(loss * 0.5);
    }
}

extern "C" void kernel_launch(void* const* d_in, const int* in_sizes, int n_in,
                              void* d_out, int out_size, void* d_ws, size_t ws_size,
                              hipStream_t stream) {
    const float* ini  = (const float*)d_in[0];
    const float* pp   = (const float*)d_in[1];
    const float* gt   = (const float*)d_in[2];
    const float* mask = (const float*)d_in[3];
    float* out = (float*)d_out;

    const int B = in_sizes[0] / (NP * 2);
    float* partial = (float*)d_ws;

    dm_main<<<B, 512, 0, stream>>>(ini, pp, gt, mask, partial);
    const double inv_count = 1.0 / ((double)B * NP * 2);
    dm_final<<<1, 256, 0, stream>>>(partial, B, inv_count, out);
}